// Round 6
// baseline (4504.903 us; speedup 1.0000x reference)
//
#include <hip/hip_runtime.h>
#include <cstdint>
#include <cstddef>

// ---------------------------------------------------------------------------
// ActorNetSpiking: chunked layer pipeline. FC layers as exact-order f32 VALU
// GEMM: lane=n, weights in VGPRs (VMEM, prefetchable), A spike-floats read
// over the scalar path (uniform s_load -> SGPR operand). One v_fma per MAC.
// Per-output arithmetic: k-ascending single-accumulator fma chain + bias,
// bit-identical to the validated round-0/4/5 numerics.
// ---------------------------------------------------------------------------

#define NB 4096
#define MTOT (NB * 50)

__device__ __forceinline__ void neuron_update(float syn, float& u, float& v, float& s) {
    u = u * 0.5f + syn;
    v = v * 0.75f * (1.0f - s) + u;
    s = (v > 0.5f) ? 1.0f : 0.0f;
}

// ------------------------- conv1: (B,1,360) -> (B,5,178) --------------------
__global__ __launch_bounds__(192) void conv1_kernel(
    const float* __restrict__ x, const float* __restrict__ w1,
    const float* __restrict__ b1, unsigned long long* __restrict__ S1)
{
    __shared__ float xl[9000];
    const int tid = threadIdx.x;
    const int b = blockIdx.x;                 // chunk-local
    const int j = tid;
    const int lbase = (j < 178) ? 2 * j : 354;

    float wr[25], br[5];
#pragma unroll
    for (int q = 0; q < 25; ++q) wr[q] = w1[q];
#pragma unroll
    for (int o = 0; o < 5; ++o) br[o] = b1[o];

    float u[5], v[5], s[5];
#pragma unroll
    for (int o = 0; o < 5; ++o) { u[o] = 0.f; v[o] = 0.f; s[o] = 0.f; }

    const float* xb = x + (size_t)b * 18000;
    for (int half = 0; half < 2; ++half) {
        const int t0 = half * 25;
        __syncthreads();
        for (int e = tid; e < 9000; e += 192)
            xl[e] = xb[(e / 25) * 50 + t0 + (e % 25)];
        __syncthreads();
        for (int dt = 0; dt < 25; ++dt) {
            const int t = t0 + dt;
            float xv[5];
#pragma unroll
            for (int k = 0; k < 5; ++k) xv[k] = xl[(lbase + k) * 25 + dt];
#pragma unroll
            for (int o = 0; o < 5; ++o) {
                float syn = 0.f;
#pragma unroll
                for (int k = 0; k < 5; ++k) syn += wr[o * 5 + k] * xv[k];
                syn += br[o];
                neuron_update(syn, u[o], v[o], s[o]);
                unsigned long long m = __ballot(j < 178 && s[o] > 0.5f);
                if ((tid & 63) == 0)
                    S1[(((size_t)b * 50 + t) * 5 + o) * 3 + (tid >> 6)] = m;
            }
        }
    }
}

// ------------------------- conv2: (B,5,178) -> (B,5,87) ---------------------
__global__ __launch_bounds__(128) void conv2_kernel(
    const unsigned int* __restrict__ S1, const float* __restrict__ w2,
    const float* __restrict__ b2, unsigned int* __restrict__ S2)
{
    __shared__ unsigned int s1l[1501];
    const int tid = threadIdx.x;
    const int b = blockIdx.x;

    float wr[125], br[5];
#pragma unroll
    for (int q = 0; q < 125; ++q) wr[q] = w2[q];
#pragma unroll
    for (int o = 0; o < 5; ++o) br[o] = b2[o];

    const unsigned int* src = S1 + (size_t)b * 1500;
    for (int e = tid; e < 1500; e += 128) s1l[e] = src[e];
    __syncthreads();

    const int p = (tid < 87) ? 2 * tid : 172;
    const int pw = p >> 5, ps = p & 31;

    float u[5], v[5], s[5];
#pragma unroll
    for (int o = 0; o < 5; ++o) { u[o] = 0.f; v[o] = 0.f; s[o] = 0.f; }

    for (int t = 0; t < 50; ++t) {
        float xv[25];
#pragma unroll
        for (int ci = 0; ci < 5; ++ci) {
            const int base = (t * 5 + ci) * 6 + pw;
            unsigned long long bits =
                ((((unsigned long long)s1l[base + 1]) << 32) | (unsigned long long)s1l[base]) >> ps;
#pragma unroll
            for (int k = 0; k < 5; ++k)
                xv[ci * 5 + k] = ((bits >> k) & 1ULL) ? 1.0f : 0.0f;
        }
#pragma unroll
        for (int o = 0; o < 5; ++o) {
            float syn = 0.f;
#pragma unroll
            for (int q = 0; q < 25; ++q) syn += wr[o * 25 + q] * xv[q];
            syn += br[o];
            neuron_update(syn, u[o], v[o], s[o]);
            unsigned long long m = __ballot(tid < 87 && s[o] > 0.5f);
            const size_t outb = (((size_t)b * 50 + t) * 5 + o) * 3;
            if (tid == 0) {
                S2[outb]     = (unsigned int)m;
                S2[outb + 1] = (unsigned int)(m >> 32);
            }
            if (tid == 64) S2[outb + 2] = (unsigned int)m;
        }
    }
}

// ------------------------- conv3: (B,5,87) -> A0 floats (rows of 224) -------
// A0[m][k]: k=0..209 conv3 spikes (k=o*42+j), 210..215 normal spikes (raw
// copy, exact), 216..223 zero pad.
__global__ __launch_bounds__(64) void conv3_kernel(
    const unsigned int* __restrict__ S2, const float* __restrict__ w3,
    const float* __restrict__ b3, const float* __restrict__ normal,
    float* __restrict__ A0)
{
    __shared__ unsigned int s2l[751];
    const int tid = threadIdx.x;
    const int b = blockIdx.x;                 // chunk-local

    float wr[125], br[5];
#pragma unroll
    for (int q = 0; q < 125; ++q) wr[q] = w3[q];
#pragma unroll
    for (int o = 0; o < 5; ++o) br[o] = b3[o];

    const unsigned int* src = S2 + (size_t)b * 750;
    for (int e = tid; e < 750; e += 64) s2l[e] = src[e];
    __syncthreads();

    const int p = (tid < 42) ? 2 * tid : 82;
    const int pw = p >> 5, ps = p & 31;

    float u[5], v[5], s[5];
#pragma unroll
    for (int o = 0; o < 5; ++o) { u[o] = 0.f; v[o] = 0.f; s[o] = 0.f; }

    for (int t = 0; t < 50; ++t) {
        float xv[25];
#pragma unroll
        for (int ci = 0; ci < 5; ++ci) {
            const int base = (t * 5 + ci) * 3 + pw;
            unsigned long long bits =
                ((((unsigned long long)s2l[base + 1]) << 32) | (unsigned long long)s2l[base]) >> ps;
#pragma unroll
            for (int k = 0; k < 5; ++k)
                xv[ci * 5 + k] = ((bits >> k) & 1ULL) ? 1.0f : 0.0f;
        }
        float* arow = A0 + ((size_t)b * 50 + t) * 224;
#pragma unroll
        for (int o = 0; o < 5; ++o) {
            float syn = 0.f;
#pragma unroll
            for (int q = 0; q < 25; ++q) syn += wr[o * 25 + q] * xv[q];
            syn += br[o];
            neuron_update(syn, u[o], v[o], s[o]);
            if (tid < 42) arow[o * 42 + tid] = s[o];
        }
        if (tid < 6)  arow[210 + tid] = normal[((size_t)b * 6 + tid) * 50 + t];
        if (tid < 8)  arow[216 + tid] = 0.f;
    }
}

// ------------------------- weight transpose prep ----------------------------
__global__ __launch_bounds__(256) void transpose_w_kernel(
    const float* __restrict__ W, float* __restrict__ Wt, int N, int KREAL, int KPAD)
{
    const int idx = blockIdx.x * 256 + threadIdx.x;
    if (idx >= KPAD * N) return;
    const int k = idx / N, n = idx % N;
    Wt[idx] = (k < KREAL) ? W[(size_t)n * KREAL + k] : 0.f;
}

// ------------------------- exact-order f32 GEMM -----------------------------
// lane = n; per thread: 32 m-rows, acc[32]; weights w[32] per k-chunk in
// VGPRs (VMEM); A floats read scalar (uniform address -> s_load, SGPR fma
// operand). Per output: k-ascending single-acc fma chain, bias last.
template <int NTOT, int KPAD>
__global__ __launch_bounds__(256, 4) void sgemm_f_kernel(
    const float* __restrict__ A,      // [Mloc][KPAD]
    const float* __restrict__ Wt,     // [KPAD][NTOT]
    const float* __restrict__ bias,   // (NTOT,)
    float* __restrict__ syn)          // [Mloc][NTOT]
{
    constexpr int KT = KPAD / 32;
    constexpr int GROUPS = 256 / NTOT;
    const int tid = threadIdx.x;
    const int n = tid & (NTOT - 1);
    const int grp = tid / NTOT;                            // wave-uniform
    const int mbase = __builtin_amdgcn_readfirstlane(
        blockIdx.x * (32 * GROUPS) + grp * 32);

    const float* aBase = A + (size_t)mbase * KPAD;

    float acc[32];
#pragma unroll
    for (int i = 0; i < 32; ++i) acc[i] = 0.f;

    for (int kt = 0; kt < KT; ++kt) {
        float w[32];
#pragma unroll
        for (int kk = 0; kk < 32; ++kk)
            w[kk] = Wt[(size_t)(kt * 32 + kk) * NTOT + n];
#pragma unroll
        for (int mi = 0; mi < 32; ++mi) {
            const float* ar = aBase + mi * KPAD + kt * 32;  // uniform address
#pragma unroll
            for (int kk = 0; kk < 32; ++kk)
                acc[mi] = fmaf(ar[kk], w[kk], acc[mi]);     // sgpr * vgpr + vgpr
        }
    }

    const float bs = bias[n];
#pragma unroll
    for (int mi = 0; mi < 32; ++mi)
        syn[(size_t)(mbase + mi) * NTOT + n] = acc[mi] + bs;
}

// ------------------------- FC scan (N=256): LIF, emit spike floats ----------
__global__ __launch_bounds__(256) void fc_scanF_kernel(
    const float* __restrict__ syn,    // [chunk*50][256]
    float* __restrict__ Aout)         // [chunk*50][256]
{
    const int o = threadIdx.x;
    const int bl = blockIdx.x;
    float u = 0.f, v = 0.f, s = 0.f;
    for (int t = 0; t < 50; ++t) {
        const size_t r = (size_t)bl * 50 + t;
        neuron_update(syn[r * 256 + o], u, v, s);
        Aout[r * 256 + o] = s;
    }
}

// ------------------------- FC scan (N=128): LIF, emit bit rows --------------
__global__ __launch_bounds__(256) void fc_scan128_kernel(
    const float* __restrict__ syn,             // [chunk*50][128]
    unsigned long long* __restrict__ SF,       // [MTOT][2] u64 (global)
    int b0)
{
    const int tid = threadIdx.x;
    const int wid = blockIdx.x * 4 + (tid >> 6);
    const int lane = tid & 63;
    const int bl = wid >> 1;
    const int ob = wid & 1;
    const int o = ob * 64 + lane;

    float u = 0.f, v = 0.f, s = 0.f;
    for (int t = 0; t < 50; ++t) {
        const float sv = syn[((size_t)bl * 50 + t) * 128 + o];
        neuron_update(sv, u, v, s);
        const unsigned long long m = __ballot(s > 0.5f);
        if (lane == 0) SF[((size_t)(b0 + bl) * 50 + t) * 2 + ob] = m;
    }
}

// ------------------------- fc4 GEMM (N=2, K=128) ----------------------------
__global__ __launch_bounds__(256) void fc4_gemm_kernel(
    const unsigned long long* __restrict__ SF3, const float* __restrict__ W,
    const float* __restrict__ bias, float* __restrict__ syn4)
{
    const int m = blockIdx.x * 256 + threadIdx.x;
    const unsigned long long w0 = SF3[(size_t)m * 2];
    const unsigned long long w1 = SF3[(size_t)m * 2 + 1];
    float a0 = 0.f, a1 = 0.f;
#pragma unroll
    for (int i = 0; i < 64; ++i) {
        const float bit = ((w0 >> i) & 1ULL) ? 1.f : 0.f;
        a0 = fmaf(bit, W[i], a0);
        a1 = fmaf(bit, W[128 + i], a1);
    }
#pragma unroll
    for (int i = 0; i < 64; ++i) {
        const float bit = ((w1 >> i) & 1ULL) ? 1.f : 0.f;
        a0 = fmaf(bit, W[64 + i], a0);
        a1 = fmaf(bit, W[192 + i], a1);
    }
    syn4[(size_t)m * 2]     = a0 + bias[0];
    syn4[(size_t)m * 2 + 1] = a1 + bias[1];
}

__global__ __launch_bounds__(64) void fc4_scan_kernel(
    const float* __restrict__ syn4, float* __restrict__ out)
{
    const int b = blockIdx.x * 64 + threadIdx.x;
    float u0 = 0.f, v0 = 0.f, s0 = 0.f, acc0 = 0.f;
    float u1 = 0.f, v1 = 0.f, s1 = 0.f, acc1 = 0.f;
    for (int t = 0; t < 50; ++t) {
        const float x0 = syn4[((size_t)b * 50 + t) * 2];
        const float x1 = syn4[((size_t)b * 50 + t) * 2 + 1];
        neuron_update(x0, u0, v0, s0); acc0 += s0;
        neuron_update(x1, u1, v1, s1); acc1 += s1;
    }
    out[b * 2]     = acc0 / 50.0f;
    out[b * 2 + 1] = acc1 / 50.0f;
}

// ---------------------------------------------------------------------------
extern "C" void kernel_launch(void* const* d_in, const int* in_sizes, int n_in,
                              void* d_out, int out_size, void* d_ws, size_t ws_size,
                              hipStream_t stream) {
    (void)in_sizes; (void)n_in; (void)out_size;
    const float* normal = (const float*)d_in[0];
    const float* xscan  = (const float*)d_in[1];
    const float* w1  = (const float*)d_in[3];
    const float* b1  = (const float*)d_in[4];
    const float* w2  = (const float*)d_in[5];
    const float* b2  = (const float*)d_in[6];
    const float* w3  = (const float*)d_in[7];
    const float* b3  = (const float*)d_in[8];
    const float* fw1 = (const float*)d_in[9];
    const float* fb1 = (const float*)d_in[10];
    const float* fw2 = (const float*)d_in[11];
    const float* fb2 = (const float*)d_in[12];
    const float* fw3 = (const float*)d_in[13];
    const float* fb3 = (const float*)d_in[14];
    const float* fw4 = (const float*)d_in[15];
    const float* fb4 = (const float*)d_in[16];
    float* out = (float*)d_out;

    char* wp = (char*)d_ws;
    size_t off = 0;
    auto take = [&](size_t bytes) -> void* {
        void* p = wp + off;
        off += (bytes + 255) & ~(size_t)255;
        return p;
    };
    float* Wt1 = (float*)take((size_t)224 * 256 * 4);
    float* Wt2 = (float*)take((size_t)256 * 256 * 4);
    float* Wt3 = (float*)take((size_t)256 * 128 * 4);
    unsigned long long* SF3 = (unsigned long long*)take((size_t)MTOT * 2 * 8);
    float* syn4 = (float*)take((size_t)MTOT * 2 * 4);

    // per-b chunked bytes: S1 6000 + S2 3000 + A0 44800 + Abuf 51200 + syn 51200
    const size_t PER_B = 50 * (15 * 8 + 15 * 4 + 224 * 4 + 256 * 4 + 256 * 4) + 5 * 256;
    int chunk = NB;
    while (chunk > 128 && off + (size_t)chunk * PER_B > ws_size) chunk >>= 1;

    unsigned long long* S1  = (unsigned long long*)take((size_t)chunk * 50 * 15 * 8);
    unsigned int*       S2  = (unsigned int*)take((size_t)chunk * 50 * 15 * 4);
    float* A0   = (float*)take((size_t)chunk * 50 * 224 * 4);
    float* Abuf = (float*)take((size_t)chunk * 50 * 256 * 4);
    float* syn  = (float*)take((size_t)chunk * 50 * 256 * 4);

    transpose_w_kernel<<<(224 * 256 + 255) / 256, 256, 0, stream>>>(fw1, Wt1, 256, 216, 224);
    transpose_w_kernel<<<(256 * 256 + 255) / 256, 256, 0, stream>>>(fw2, Wt2, 256, 256, 256);
    transpose_w_kernel<<<(256 * 128 + 255) / 256, 256, 0, stream>>>(fw3, Wt3, 128, 256, 256);

    for (int b0 = 0; b0 < NB; b0 += chunk) {
        conv1_kernel<<<chunk, 192, 0, stream>>>(
            xscan + (size_t)b0 * 18000, w1, b1, S1);
        conv2_kernel<<<chunk, 128, 0, stream>>>(
            (const unsigned int*)S1, w2, b2, S2);
        conv3_kernel<<<chunk, 64, 0, stream>>>(
            S2, w3, b3, normal + (size_t)b0 * 300, A0);

        sgemm_f_kernel<256, 224><<<chunk * 50 / 32, 256, 0, stream>>>(A0, Wt1, fb1, syn);
        fc_scanF_kernel<<<chunk, 256, 0, stream>>>(syn, Abuf);

        sgemm_f_kernel<256, 256><<<chunk * 50 / 32, 256, 0, stream>>>(Abuf, Wt2, fb2, syn);
        fc_scanF_kernel<<<chunk, 256, 0, stream>>>(syn, Abuf);

        sgemm_f_kernel<128, 256><<<chunk * 50 / 64, 256, 0, stream>>>(Abuf, Wt3, fb3, syn);
        fc_scan128_kernel<<<chunk / 2, 256, 0, stream>>>(syn, SF3, b0);
    }

    fc4_gemm_kernel<<<MTOT / 256, 256, 0, stream>>>(SF3, fw4, fb4, syn4);
    fc4_scan_kernel<<<NB / 64, 64, 0, stream>>>(syn4, out);
}

// Round 7
// 1600.697 us; speedup vs baseline: 2.8143x; 2.8143x over previous
//
#include <hip/hip_runtime.h>
#include <cstdint>
#include <cstddef>

// ---------------------------------------------------------------------------
// ActorNetSpiking: layer-by-layer over time; spike trains bit-packed (L2-
// resident); FC layers as exact-order GEMM: A-bits in VGPRs (expand in-reg),
// B in LDS (double-buffered global_load_lds), v_pk_fma_f32 packed dual FMA
// with op_sel broadcast. Per-output arithmetic: k-ascending single-
// accumulator IEEE-FMA chain + bias-last -- bit-identical to the validated
// round-0/4/5 numerics.
// ---------------------------------------------------------------------------

#define NB 4096
#define MTOT (NB * 50)

typedef __attribute__((ext_vector_type(2))) float f32x2;

__device__ __forceinline__ void neuron_update(float syn, float& u, float& v, float& s) {
    u = u * 0.5f + syn;
    v = v * 0.75f * (1.0f - s) + u;
    s = (v > 0.5f) ? 1.0f : 0.0f;
}

// ------------------------- conv1: (B,1,360) -> (B,5,178) --------------------
__global__ __launch_bounds__(192) void conv1_kernel(
    const float* __restrict__ x, const float* __restrict__ w1,
    const float* __restrict__ b1, unsigned long long* __restrict__ S1)
{
    __shared__ float xl[9000];
    const int tid = threadIdx.x;
    const int b = blockIdx.x;
    const int j = tid;
    const int lbase = (j < 178) ? 2 * j : 354;

    float wr[25], br[5];
#pragma unroll
    for (int q = 0; q < 25; ++q) wr[q] = w1[q];
#pragma unroll
    for (int o = 0; o < 5; ++o) br[o] = b1[o];

    float u[5], v[5], s[5];
#pragma unroll
    for (int o = 0; o < 5; ++o) { u[o] = 0.f; v[o] = 0.f; s[o] = 0.f; }

    const float* xb = x + (size_t)b * 18000;
    for (int half = 0; half < 2; ++half) {
        const int t0 = half * 25;
        __syncthreads();
        for (int e = tid; e < 9000; e += 192)
            xl[e] = xb[(e / 25) * 50 + t0 + (e % 25)];
        __syncthreads();
        for (int dt = 0; dt < 25; ++dt) {
            const int t = t0 + dt;
            float xv[5];
#pragma unroll
            for (int k = 0; k < 5; ++k) xv[k] = xl[(lbase + k) * 25 + dt];
#pragma unroll
            for (int o = 0; o < 5; ++o) {
                float syn = 0.f;
#pragma unroll
                for (int k = 0; k < 5; ++k) syn += wr[o * 5 + k] * xv[k];
                syn += br[o];
                neuron_update(syn, u[o], v[o], s[o]);
                unsigned long long m = __ballot(j < 178 && s[o] > 0.5f);
                if ((tid & 63) == 0)
                    S1[(((size_t)b * 50 + t) * 5 + o) * 3 + (tid >> 6)] = m;
            }
        }
    }
}

// ------------------------- conv2: (B,5,178) -> (B,5,87) ---------------------
__global__ __launch_bounds__(128) void conv2_kernel(
    const unsigned int* __restrict__ S1, const float* __restrict__ w2,
    const float* __restrict__ b2, unsigned int* __restrict__ S2)
{
    __shared__ unsigned int s1l[1501];
    const int tid = threadIdx.x;
    const int b = blockIdx.x;

    float wr[125], br[5];
#pragma unroll
    for (int q = 0; q < 125; ++q) wr[q] = w2[q];
#pragma unroll
    for (int o = 0; o < 5; ++o) br[o] = b2[o];

    const unsigned int* src = S1 + (size_t)b * 1500;
    for (int e = tid; e < 1500; e += 128) s1l[e] = src[e];
    __syncthreads();

    const int p = (tid < 87) ? 2 * tid : 172;
    const int pw = p >> 5, ps = p & 31;

    float u[5], v[5], s[5];
#pragma unroll
    for (int o = 0; o < 5; ++o) { u[o] = 0.f; v[o] = 0.f; s[o] = 0.f; }

    for (int t = 0; t < 50; ++t) {
        float xv[25];
#pragma unroll
        for (int ci = 0; ci < 5; ++ci) {
            const int base = (t * 5 + ci) * 6 + pw;
            unsigned long long bits =
                ((((unsigned long long)s1l[base + 1]) << 32) | (unsigned long long)s1l[base]) >> ps;
#pragma unroll
            for (int k = 0; k < 5; ++k)
                xv[ci * 5 + k] = ((bits >> k) & 1ULL) ? 1.0f : 0.0f;
        }
#pragma unroll
        for (int o = 0; o < 5; ++o) {
            float syn = 0.f;
#pragma unroll
            for (int q = 0; q < 25; ++q) syn += wr[o * 25 + q] * xv[q];
            syn += br[o];
            neuron_update(syn, u[o], v[o], s[o]);
            unsigned long long m = __ballot(tid < 87 && s[o] > 0.5f);
            const size_t outb = (((size_t)b * 50 + t) * 5 + o) * 3;
            if (tid == 0) {
                S2[outb]     = (unsigned int)m;
                S2[outb + 1] = (unsigned int)(m >> 32);
            }
            if (tid == 64) S2[outb + 2] = (unsigned int)m;
        }
    }
}

// ------------------------- conv3: (B,5,87) -> transposed 216-bit rows -------
// Row m = b*50+t: bits k=0..209 conv3 spikes (k=o*42+j), 210..215 normal.
// Stored transposed: ST0[w*MTOT + m] = word w.
__global__ __launch_bounds__(64) void conv3_kernel(
    const unsigned int* __restrict__ S2, const float* __restrict__ w3,
    const float* __restrict__ b3, const float* __restrict__ normal,
    unsigned int* __restrict__ ST0)
{
    __shared__ unsigned int s2l[751];
    const int tid = threadIdx.x;
    const int b = blockIdx.x;

    float wr[125], br[5];
#pragma unroll
    for (int q = 0; q < 125; ++q) wr[q] = w3[q];
#pragma unroll
    for (int o = 0; o < 5; ++o) br[o] = b3[o];

    const unsigned int* src = S2 + (size_t)b * 750;
    for (int e = tid; e < 750; e += 64) s2l[e] = src[e];
    __syncthreads();

    const int p = (tid < 42) ? 2 * tid : 82;
    const int pw = p >> 5, ps = p & 31;

    float u[5], v[5], s[5];
#pragma unroll
    for (int o = 0; o < 5; ++o) { u[o] = 0.f; v[o] = 0.f; s[o] = 0.f; }

    for (int t = 0; t < 50; ++t) {
        float xv[25];
#pragma unroll
        for (int ci = 0; ci < 5; ++ci) {
            const int base = (t * 5 + ci) * 3 + pw;
            unsigned long long bits =
                ((((unsigned long long)s2l[base + 1]) << 32) | (unsigned long long)s2l[base]) >> ps;
#pragma unroll
            for (int k = 0; k < 5; ++k)
                xv[ci * 5 + k] = ((bits >> k) & 1ULL) ? 1.0f : 0.0f;
        }
        unsigned long long m[5];
#pragma unroll
        for (int o = 0; o < 5; ++o) {
            float syn = 0.f;
#pragma unroll
            for (int q = 0; q < 25; ++q) syn += wr[o * 25 + q] * xv[q];
            syn += br[o];
            neuron_update(syn, u[o], v[o], s[o]);
            m[o] = __ballot(tid < 42 && s[o] > 0.5f);
        }
        const unsigned long long nm =
            __ballot(tid < 6 && normal[((size_t)b * 6 + tid) * 50 + t] > 0.5f);
        if (tid == 0) {
            const unsigned long long r0 = m[0] | (m[1] << 42);
            const unsigned long long r1 = (m[1] >> 22) | (m[2] << 20) | (m[3] << 62);
            const unsigned long long r2 = (m[3] >> 2) | (m[4] << 40);
            const unsigned long long r3 = (m[4] >> 24) | (nm << 18);
            const size_t mrow = (size_t)b * 50 + t;
            ST0[0 * (size_t)MTOT + mrow] = (unsigned int)r0;
            ST0[1 * (size_t)MTOT + mrow] = (unsigned int)(r0 >> 32);
            ST0[2 * (size_t)MTOT + mrow] = (unsigned int)r1;
            ST0[3 * (size_t)MTOT + mrow] = (unsigned int)(r1 >> 32);
            ST0[4 * (size_t)MTOT + mrow] = (unsigned int)r2;
            ST0[5 * (size_t)MTOT + mrow] = (unsigned int)(r2 >> 32);
            ST0[6 * (size_t)MTOT + mrow] = (unsigned int)r3;
        }
    }
}

// ------------------------- weight transpose prep ----------------------------
__global__ __launch_bounds__(256) void transpose_w_kernel(
    const float* __restrict__ W, float* __restrict__ Wt, int N, int KREAL, int KPAD)
{
    const int idx = blockIdx.x * 256 + threadIdx.x;
    if (idx >= KPAD * N) return;
    const int k = idx / N, n = idx % N;
    Wt[idx] = (k < KREAL) ? W[(size_t)n * KREAL + k] : 0.f;
}

// ------------------------- pk GEMM: A-bits in VGPR, B in LDS ----------------
// Tile 256m x 128n, 256 threads (tm=tid&15 m-group of 16, tn=tid>>4 n-group
// of 8). Per kk: expand 16 a-bits (bfe+cvt), 4x ds_read_b64 (w pairs),
// 64x v_pk_fma_f32 (acc paired along n, a broadcast via op_sel_hi[0]=0).
template <int NTOT, int KT>
__global__ __launch_bounds__(256, 2) void pk_gemm_kernel(
    const uint32_t* __restrict__ bitsT,   // [>=KT][MTOT] u32 planes
    const float* __restrict__ Wt,         // [KT*32][NTOT]
    const float* __restrict__ bias,       // (NTOT,)
    float* __restrict__ syn,              // [Mchunk][NTOT]
    int row0)
{
    __shared__ __align__(16) float blds[2][32 * 128];   // 16KB x 2

    const int tid = threadIdx.x;
    const int lane = tid & 63;
    const int wid = tid >> 6;
    const int tm = tid & 15;
    const int tn = tid >> 4;
    const int m0 = blockIdx.x * 256;
    const int nbase = blockIdx.y * 128;

    // ---- B staging: [32 k][128 n] f32 = 16KB, 4 x global_load_lds(16B) ----
    auto stage = [&](int kt, int buf) {
#pragma unroll
        for (int j = 0; j < 4; ++j) {
            const int c = (j * 4 + wid) * 64 + lane;        // 16B chunk id
            const int row = c >> 5, col = c & 31;
            const float* src = Wt + (size_t)(kt * 32 + row) * NTOT + nbase + col * 4;
            float* dst = &blds[buf][0] + (size_t)(j * 4 + wid) * 256 + lane * 4;
            __builtin_amdgcn_global_load_lds(
                (const __attribute__((address_space(1))) uint32_t*)src,
                (__attribute__((address_space(3))) uint32_t*)dst, 16, 0, 0);
        }
    };

    const int rowA = row0 + m0 + tm * 16;
    auto loadA = [&](int kt, uint4& q0, uint4& q1, uint4& q2, uint4& q3) {
        const uint32_t* p = bitsT + (size_t)kt * MTOT + rowA;
        q0 = *reinterpret_cast<const uint4*>(p);
        q1 = *reinterpret_cast<const uint4*>(p + 4);
        q2 = *reinterpret_cast<const uint4*>(p + 8);
        q3 = *reinterpret_cast<const uint4*>(p + 12);
    };

    uint4 A0, A1, A2, A3, N0, N1, N2, N3;
    loadA(0, A0, A1, A2, A3);
    stage(0, 0);

    f32x2 acc[16][4];
#pragma unroll
    for (int mi = 0; mi < 16; ++mi)
#pragma unroll
        for (int r2 = 0; r2 < 4; ++r2) acc[mi][r2] = (f32x2){0.f, 0.f};

    for (int kt = 0; kt < KT; ++kt) {
        __syncthreads();   // drains vmcnt: buf[kt&1] + A regs ready; prev reads done
        if (kt + 1 < KT) {
            stage(kt + 1, (kt + 1) & 1);
            loadA(kt + 1, N0, N1, N2, N3);
        }

        uint awv[16] = {A0.x, A0.y, A0.z, A0.w, A1.x, A1.y, A1.z, A1.w,
                        A2.x, A2.y, A2.z, A2.w, A3.x, A3.y, A3.z, A3.w};
        const float* bt = &blds[kt & 1][0];

#pragma unroll
        for (int kk = 0; kk < 32; ++kk) {
            f32x2 w2[4];
#pragma unroll
            for (int r2 = 0; r2 < 4; ++r2)
                w2[r2] = *reinterpret_cast<const f32x2*>(bt + kk * 128 + tn * 8 + r2 * 2);
            f32x2 av = {0.f, 0.f};
#pragma unroll
            for (int mi = 0; mi < 16; ++mi) {
                av.x = (float)((awv[mi] >> kk) & 1u);
#pragma unroll
                for (int r2 = 0; r2 < 4; ++r2)
                    asm("v_pk_fma_f32 %0, %1, %2, %0 op_sel_hi:[0,1,1]"
                        : "+v"(acc[mi][r2]) : "v"(av), "v"(w2[r2]));
            }
        }
        if (kt + 1 < KT) { A0 = N0; A1 = N1; A2 = N2; A3 = N3; }
    }

    // ---- epilogue: bias-last, coalesced float4 stores ----
    const int nb = nbase + tn * 8;
    float bsv[8];
#pragma unroll
    for (int q = 0; q < 8; ++q) bsv[q] = bias[nb + q];
#pragma unroll
    for (int mi = 0; mi < 16; ++mi) {
        float* so = syn + (size_t)(m0 + tm * 16 + mi) * NTOT + nb;
        float4 o0, o1;
        o0.x = acc[mi][0].x + bsv[0]; o0.y = acc[mi][0].y + bsv[1];
        o0.z = acc[mi][1].x + bsv[2]; o0.w = acc[mi][1].y + bsv[3];
        o1.x = acc[mi][2].x + bsv[4]; o1.y = acc[mi][2].y + bsv[5];
        o1.z = acc[mi][3].x + bsv[6]; o1.w = acc[mi][3].y + bsv[7];
        *reinterpret_cast<float4*>(so) = o0;
        *reinterpret_cast<float4*>(so + 4) = o1;
    }
}

// ------------------------- FC scan (N=256): LIF -> transposed bit planes ----
__global__ __launch_bounds__(256) void fc_scanT_kernel(
    const float* __restrict__ syn, uint32_t* __restrict__ SFT, int b0)
{
    const int tid = threadIdx.x;
    const int lane = tid & 63;
    const int ob = tid >> 6;
    const int bl = blockIdx.x;
    const int o = ob * 64 + lane;

    float u = 0.f, v = 0.f, s = 0.f;
    for (int t = 0; t < 50; ++t) {
        const float sv = syn[((size_t)bl * 50 + t) * 256 + o];
        neuron_update(sv, u, v, s);
        const unsigned long long m = __ballot(s > 0.5f);
        if (lane == 0) {
            const size_t row = (size_t)(b0 + bl) * 50 + t;
            SFT[(size_t)(2 * ob) * MTOT + row]     = (uint32_t)m;
            SFT[(size_t)(2 * ob + 1) * MTOT + row] = (uint32_t)(m >> 32);
        }
    }
}

// ------------------------- FC scan (N=128): LIF -> u64 rows -----------------
__global__ __launch_bounds__(256) void fc_scan128_kernel(
    const float* __restrict__ syn, unsigned long long* __restrict__ SF, int b0)
{
    const int tid = threadIdx.x;
    const int wid = blockIdx.x * 4 + (tid >> 6);
    const int lane = tid & 63;
    const int bl = wid >> 1;
    const int ob = wid & 1;
    const int o = ob * 64 + lane;

    float u = 0.f, v = 0.f, s = 0.f;
    for (int t = 0; t < 50; ++t) {
        const float sv = syn[((size_t)bl * 50 + t) * 128 + o];
        neuron_update(sv, u, v, s);
        const unsigned long long m = __ballot(s > 0.5f);
        if (lane == 0) SF[((size_t)(b0 + bl) * 50 + t) * 2 + ob] = m;
    }
}

// ------------------------- fc4 GEMM (N=2, K=128) ----------------------------
__global__ __launch_bounds__(256) void fc4_gemm_kernel(
    const unsigned long long* __restrict__ SF3, const float* __restrict__ W,
    const float* __restrict__ bias, float* __restrict__ syn4)
{
    const int m = blockIdx.x * 256 + threadIdx.x;
    const unsigned long long w0 = SF3[(size_t)m * 2];
    const unsigned long long w1 = SF3[(size_t)m * 2 + 1];
    float a0 = 0.f, a1 = 0.f;
#pragma unroll
    for (int i = 0; i < 64; ++i) {
        const float bit = ((w0 >> i) & 1ULL) ? 1.f : 0.f;
        a0 = fmaf(bit, W[i], a0);
        a1 = fmaf(bit, W[128 + i], a1);
    }
#pragma unroll
    for (int i = 0; i < 64; ++i) {
        const float bit = ((w1 >> i) & 1ULL) ? 1.f : 0.f;
        a0 = fmaf(bit, W[64 + i], a0);
        a1 = fmaf(bit, W[192 + i], a1);
    }
    syn4[(size_t)m * 2]     = a0 + bias[0];
    syn4[(size_t)m * 2 + 1] = a1 + bias[1];
}

__global__ __launch_bounds__(64) void fc4_scan_kernel(
    const float* __restrict__ syn4, float* __restrict__ out)
{
    const int b = blockIdx.x * 64 + threadIdx.x;
    float u0 = 0.f, v0 = 0.f, s0 = 0.f, acc0 = 0.f;
    float u1 = 0.f, v1 = 0.f, s1 = 0.f, acc1 = 0.f;
    for (int t = 0; t < 50; ++t) {
        const float x0 = syn4[((size_t)b * 50 + t) * 2];
        const float x1 = syn4[((size_t)b * 50 + t) * 2 + 1];
        neuron_update(x0, u0, v0, s0); acc0 += s0;
        neuron_update(x1, u1, v1, s1); acc1 += s1;
    }
    out[b * 2]     = acc0 / 50.0f;
    out[b * 2 + 1] = acc1 / 50.0f;
}

// ---------------------------------------------------------------------------
extern "C" void kernel_launch(void* const* d_in, const int* in_sizes, int n_in,
                              void* d_out, int out_size, void* d_ws, size_t ws_size,
                              hipStream_t stream) {
    (void)in_sizes; (void)n_in; (void)out_size;
    const float* normal = (const float*)d_in[0];
    const float* xscan  = (const float*)d_in[1];
    const float* w1  = (const float*)d_in[3];
    const float* b1  = (const float*)d_in[4];
    const float* w2  = (const float*)d_in[5];
    const float* b2  = (const float*)d_in[6];
    const float* w3  = (const float*)d_in[7];
    const float* b3  = (const float*)d_in[8];
    const float* fw1 = (const float*)d_in[9];
    const float* fb1 = (const float*)d_in[10];
    const float* fw2 = (const float*)d_in[11];
    const float* fb2 = (const float*)d_in[12];
    const float* fw3 = (const float*)d_in[13];
    const float* fb3 = (const float*)d_in[14];
    const float* fw4 = (const float*)d_in[15];
    const float* fb4 = (const float*)d_in[16];
    float* out = (float*)d_out;

    char* wp = (char*)d_ws;
    size_t off = 0;
    auto take = [&](size_t bytes) -> void* {
        void* p = wp + off;
        off += (bytes + 255) & ~(size_t)255;
        return p;
    };
    float* Wt1 = (float*)take((size_t)224 * 256 * 4);
    float* Wt2 = (float*)take((size_t)256 * 256 * 4);
    float* Wt3 = (float*)take((size_t)256 * 128 * 4);
    unsigned long long* S1  = (unsigned long long*)take((size_t)NB * 50 * 15 * 8);
    unsigned int*       S2  = (unsigned int*)take((size_t)NB * 50 * 15 * 4);
    uint32_t* ST0 = (uint32_t*)take((size_t)8 * MTOT * 4);
    uint32_t* ST1 = (uint32_t*)take((size_t)8 * MTOT * 4);
    uint32_t* ST2 = (uint32_t*)take((size_t)8 * MTOT * 4);
    unsigned long long* SF3 = (unsigned long long*)take((size_t)MTOT * 2 * 8);
    float*              syn4 = (float*)take((size_t)MTOT * 2 * 4);

    int chunk = NB;
    while (chunk > 128 && off + (size_t)chunk * 50 * 256 * 4 > ws_size) chunk >>= 1;
    float* syn = (float*)take((size_t)chunk * 50 * 256 * 4);

    transpose_w_kernel<<<(224 * 256 + 255) / 256, 256, 0, stream>>>(fw1, Wt1, 256, 216, 224);
    transpose_w_kernel<<<(256 * 256 + 255) / 256, 256, 0, stream>>>(fw2, Wt2, 256, 256, 256);
    transpose_w_kernel<<<(256 * 128 + 255) / 256, 256, 0, stream>>>(fw3, Wt3, 128, 256, 256);

    conv1_kernel<<<NB, 192, 0, stream>>>(xscan, w1, b1, S1);
    conv2_kernel<<<NB, 128, 0, stream>>>((const unsigned int*)S1, w2, b2, S2);
    conv3_kernel<<<NB, 64, 0, stream>>>(S2, w3, b3, normal, ST0);

    for (int b0 = 0; b0 < NB; b0 += chunk) {
        pk_gemm_kernel<256, 7><<<dim3(chunk * 50 / 256, 2), 256, 0, stream>>>(
            ST0, Wt1, fb1, syn, b0 * 50);
        fc_scanT_kernel<<<chunk, 256, 0, stream>>>(syn, ST1, b0);

        pk_gemm_kernel<256, 8><<<dim3(chunk * 50 / 256, 2), 256, 0, stream>>>(
            ST1, Wt2, fb2, syn, b0 * 50);
        fc_scanT_kernel<<<chunk, 256, 0, stream>>>(syn, ST2, b0);

        pk_gemm_kernel<128, 8><<<dim3(chunk * 50 / 256, 1), 256, 0, stream>>>(
            ST2, Wt3, fb3, syn, b0 * 50);
        fc_scan128_kernel<<<chunk / 2, 256, 0, stream>>>(syn, SF3, b0);
    }

    fc4_gemm_kernel<<<MTOT / 256, 256, 0, stream>>>(SF3, fw4, fb4, syn4);
    fc4_scan_kernel<<<NB / 64, 64, 0, stream>>>(syn4, out);
}